// Round 8
// baseline (240.386 us; speedup 1.0000x reference)
//
#include <hip/hip_runtime.h>

#define NN 50000
#define EE 800000
#define FIN 256
#define HD 8
#define C1 16
#define HC 128         // HD*C1
#define NC 40
#define NEG 0.2f
#define CAP 64         // ELL capacity per node; P(Poisson(16) >= 64) ~ 1e-17
#define BM 64          // gemm1 row tile (4 waves x 16 rows)
#define BM2 64         // gemm2 row tile
#define GB1 ((NN + BM - 1) / BM)  // 782 blocks
#define NP_N (NN / 8)  // nodes per partition (6250)
#define SCB 2048       // scatter blocks (8 partitions x 256 ranks), in k_prep dispatch
#define PREPB 19       // 16 W1-swizzle blocks + 3 W2-swizzle blocks
#define CONVB 1024     // x->bf16 conversion blocks (only when ws fits xb)

typedef __attribute__((ext_vector_type(8))) short short8;   // 8 bf16 (4 VGPRs)
typedef __attribute__((ext_vector_type(4))) float f32x4;    // MFMA C/D
union FragU { uint4 u; short8 s; };

__device__ __forceinline__ float leaky(float v){ return v > 0.f ? v : NEG * v; }

// fp32 -> bf16 round-to-nearest-even (no NaNs in this workload)
__device__ __forceinline__ unsigned int f2bf(float f){
  unsigned int u = __float_as_uint(f);
  u += 0x7fffu + ((u >> 16) & 1u);
  return u >> 16;
}
__device__ __forceinline__ unsigned int pack2bf(float a, float b){
  return f2bf(a) | (f2bf(b) << 16);
}
__device__ __forceinline__ float bflo(unsigned int u){ return __uint_as_float(u << 16); }
__device__ __forceinline__ float bfhi(unsigned int u){ return __uint_as_float(u & 0xffff0000u); }
__device__ __forceinline__ float bfus(unsigned short u){ return __uint_as_float((unsigned int)u << 16); }

// async 16B global->LDS (DMA, no VGPR round-trip). LDS dest = uniform base + lane*16.
__device__ __forceinline__ void gld_lds16(const void* g, void* l){
  __builtin_amdgcn_global_load_lds((const __attribute__((address_space(1))) unsigned int*)g,
                                   (__attribute__((address_space(3))) unsigned int*)l,
                                   16, 0, 0);
}

// K0 (4 roles by blockIdx):
//  0..15            : W1 (fp32 [256][128]) -> MFMA B-fragments (bf16).
//  16..18           : W2 (fp32 [128][40])  -> MFMA B-fragments, N padded to 48.
//  19..19+convb-1   : x (fp32) -> xb (bf16), streaming (overlaps the scatter).
//  rest             : XCD-partitioned ELL edge scatter at high occupancy.
__global__ __launch_bounds__(256) void k_prep(const float* __restrict__ W1,
                                              uint4* __restrict__ W1bfs,
                                              const float* __restrict__ W2,
                                              uint4* __restrict__ W2bfs,
                                              const float* __restrict__ x,
                                              uint4* __restrict__ xb,
                                              int convb,
                                              const int* __restrict__ ei,
                                              int* __restrict__ cnt,
                                              int* __restrict__ srcp){
  const int tid = threadIdx.x;
  if (blockIdx.x < 16){
    int f = blockIdx.x * 256 + tid;   // 0..4095
    int lane = f & 63, nt = (f >> 6) & 7, kt = f >> 9;
    int quad = lane >> 4, l16 = lane & 15;
    const float* src = W1 + (size_t)(kt * 32 + quad * 8) * HC + nt * 16 + l16;
    unsigned int p[4];
#pragma unroll
    for (int jj = 0; jj < 4; jj++)
      p[jj] = pack2bf(src[(size_t)(2 * jj) * HC], src[(size_t)(2 * jj + 1) * HC]);
    W1bfs[f] = make_uint4(p[0], p[1], p[2], p[3]);
    return;
  }
  if (blockIdx.x < PREPB){
    int f = (blockIdx.x - 16) * 256 + tid;   // 0..767 = 12 fragments x 64 lanes
    int lane = f & 63, frag = f >> 6;        // frag = kt*3 + nt
    int kt = frag / 3, nt = frag - kt * 3;
    int quad = lane >> 4, l16 = lane & 15;
    int n = nt * 16 + l16;                   // output col, pad >= NC with zeros
    int k0 = kt * 32 + quad * 8;
    unsigned int p[4];
#pragma unroll
    for (int jj = 0; jj < 4; jj++){
      float v0 = (n < NC) ? W2[(size_t)(k0 + 2 * jj) * NC + n] : 0.f;
      float v1 = (n < NC) ? W2[(size_t)(k0 + 2 * jj + 1) * NC + n] : 0.f;
      p[jj] = pack2bf(v0, v1);
    }
    W2bfs[f] = make_uint4(p[0], p[1], p[2], p[3]);
    return;
  }
  if (blockIdx.x < PREPB + convb){   // x -> bf16 (grid-stride over 8-elem groups)
    const int cb = blockIdx.x - PREPB;
    const int stride = convb * 256;
    for (int idx = cb * 256 + tid; idx < NN * FIN / 8; idx += stride){
      const float4 v0 = *(const float4*)(x + (size_t)idx * 8);
      const float4 v1 = *(const float4*)(x + (size_t)idx * 8 + 4);
      xb[idx] = make_uint4(pack2bf(v0.x, v0.y), pack2bf(v0.z, v0.w),
                           pack2bf(v1.x, v1.y), pack2bf(v1.z, v1.w));
    }
    return;
  }
  const int b = blockIdx.x - PREPB - convb;  // 0..SCB-1
  const int part = b & 7, rank = b >> 3;     // each partition gets ranks 0..255
  const int lo = part * NP_N, hi = lo + NP_N;
  for (int e = rank * 256 + tid; e < EE; e += 256 * 256){
    int d = ei[EE + e];
    if (d >= lo && d < hi){
      int s = ei[e];
      int pos = atomicAdd(&cnt[d], 1);
      if (pos < CAP) srcp[d * CAP + pos] = s;   // clamp guard (never hit per Poisson tail)
    }
  }
}

// K1 (bf16 path): async-LDS GEMM h1 = xb @ W1, bf16 MFMA 16x16x32, barrier-free.
// xb rows are 512B -> 32KB LDS -> 4 blocks/CU (2x the fp32 version). A-fragment is a
// direct 16B LDS load (no pack). Source granules pre-swizzled (g ^ (row&7)).
__global__ __launch_bounds__(256, 4) void k_gemm1b(const unsigned short* __restrict__ xb,
                                                   const uint4* __restrict__ W1bfs,
                                                   const float* __restrict__ att_s,
                                                   const float* __restrict__ att_d,
                                                   unsigned short* __restrict__ h1b,
                                                   float* __restrict__ as1,
                                                   float* __restrict__ ad1){
  __shared__ unsigned short xs[BM * FIN];   // 32 KB; wave w owns rows [w*16, w*16+16)
  const int tid = threadIdx.x;
  const int wave = tid >> 6, lane = tid & 63;
  const int quad = lane >> 4, l16 = lane & 15;
  const int m0 = blockIdx.x * BM;
  const int wr0 = wave * 16;

  // stage 16 rows (512B each), 2 rows per issue: lanes 0-31 row r, 32-63 row r+1.
  // LDS granule g of local row rl holds source granule g ^ (rl&7).
#pragma unroll
  for (int i = 0; i < 8; i++){
    const int rl = wr0 + i * 2 + (lane >> 5);
    int grow = m0 + rl; if (grow >= NN) grow = NN - 1;   // clamp (dup stage benign)
    const int g = lane & 31;
    const unsigned short* src = xb + (size_t)grow * FIN + ((g ^ (rl & 7)) << 3);
    gld_lds16(src, &xs[(wr0 + i * 2) * FIN]);
  }

  FragU bf[8];
#pragma unroll
  for (int nt = 0; nt < 8; nt++) bf[nt].u = W1bfs[nt * 64 + lane];

  asm volatile("s_waitcnt vmcnt(0)" ::: "memory");
  __builtin_amdgcn_sched_barrier(0);

  f32x4 acc[8];
#pragma unroll
  for (int t = 0; t < 8; t++) acc[t] = (f32x4){0.f, 0.f, 0.f, 0.f};

  const int swz = l16 & 7;
  const unsigned short* xrow = &xs[(wr0 + l16) * FIN];
#pragma unroll
  for (int kt = 0; kt < 8; kt++){
    FragU bn[8];
    if (kt < 7){
#pragma unroll
      for (int nt = 0; nt < 8; nt++)
        bn[nt].u = W1bfs[((kt + 1) * 8 + nt) * 64 + lane];
    }
    FragU af;
    af.u = *(const uint4*)(xrow + (((kt * 4 + quad) ^ swz) << 3));   // direct A-frag
#pragma unroll
    for (int nt = 0; nt < 8; nt++)
      acc[nt] = __builtin_amdgcn_mfma_f32_16x16x32_bf16(af.s, bf[nt].s, acc[nt], 0, 0, 0);
    if (kt < 7){
#pragma unroll
      for (int nt = 0; nt < 8; nt++) bf[nt] = bn[nt];
    }
  }

  float sv[8], dv[8];
#pragma unroll
  for (int h = 0; h < 8; h++){ sv[h] = att_s[h * 16 + l16]; dv[h] = att_d[h * 16 + l16]; }
#pragma unroll
  for (int r = 0; r < 4; r++){
    const int gr = m0 + wr0 + quad * 4 + r;
    float s[8], d[8];
#pragma unroll
    for (int h = 0; h < 8; h++){ s[h] = acc[h][r] * sv[h]; d[h] = acc[h][r] * dv[h]; }
#pragma unroll
    for (int o = 1; o < 16; o <<= 1){
#pragma unroll
      for (int h = 0; h < 8; h++){ s[h] += __shfl_xor(s[h], o); d[h] += __shfl_xor(d[h], o); }
    }
    if (gr < NN){
#pragma unroll
      for (int h = 0; h < 8; h++)
        h1b[(size_t)gr * HC + h * 16 + l16] = (unsigned short)f2bf(acc[h][r]);
      if (l16 == 0){
        *(float4*)(as1 + gr * 8)     = make_float4(s[0], s[1], s[2], s[3]);
        *(float4*)(as1 + gr * 8 + 4) = make_float4(s[4], s[5], s[6], s[7]);
        *(float4*)(ad1 + gr * 8)     = make_float4(d[0], d[1], d[2], d[3]);
        *(float4*)(ad1 + gr * 8 + 4) = make_float4(d[4], d[5], d[6], d[7]);
      }
    }
  }
}

// K1 fallback (fp32 staging, round-7 kernel) — used only if ws can't fit xb.
__global__ __launch_bounds__(256, 2) void k_gemm1f(const float* __restrict__ x,
                                                   const uint4* __restrict__ W1bfs,
                                                   const float* __restrict__ att_s,
                                                   const float* __restrict__ att_d,
                                                   unsigned short* __restrict__ h1b,
                                                   float* __restrict__ as1,
                                                   float* __restrict__ ad1){
  __shared__ float xs[BM * FIN];   // 64 KB
  const int tid = threadIdx.x;
  const int wave = tid >> 6, lane = tid & 63;
  const int quad = lane >> 4, l16 = lane & 15;
  const int m0 = blockIdx.x * BM;
  const int wr0 = wave * 16;
#pragma unroll
  for (int i = 0; i < 16; i++){
    int grow = m0 + wr0 + i; if (grow >= NN) grow = NN - 1;
    const float* src = x + (size_t)grow * FIN + ((lane ^ (i & 7)) << 2);
    gld_lds16(src, &xs[(wr0 + i) * FIN]);
  }
  FragU bf[8];
#pragma unroll
  for (int nt = 0; nt < 8; nt++) bf[nt].u = W1bfs[nt * 64 + lane];
  asm volatile("s_waitcnt vmcnt(0)" ::: "memory");
  __builtin_amdgcn_sched_barrier(0);
  f32x4 acc[8];
#pragma unroll
  for (int t = 0; t < 8; t++) acc[t] = (f32x4){0.f, 0.f, 0.f, 0.f};
  const int swz = l16 & 7;
  const float* xrow = &xs[(wr0 + l16) * FIN];
#pragma unroll
  for (int kt = 0; kt < 8; kt++){
    FragU bn[8];
    if (kt < 7){
#pragma unroll
      for (int nt = 0; nt < 8; nt++)
        bn[nt].u = W1bfs[((kt + 1) * 8 + nt) * 64 + lane];
    }
    const int g0 = kt * 8 + quad * 2;
    const float4 a0 = *(const float4*)(xrow + ((g0 ^ swz) << 2));
    const float4 a1 = *(const float4*)(xrow + (((g0 + 1) ^ swz) << 2));
    FragU af;
    af.u = make_uint4(pack2bf(a0.x, a0.y), pack2bf(a0.z, a0.w),
                      pack2bf(a1.x, a1.y), pack2bf(a1.z, a1.w));
#pragma unroll
    for (int nt = 0; nt < 8; nt++)
      acc[nt] = __builtin_amdgcn_mfma_f32_16x16x32_bf16(af.s, bf[nt].s, acc[nt], 0, 0, 0);
    if (kt < 7){
#pragma unroll
      for (int nt = 0; nt < 8; nt++) bf[nt] = bn[nt];
    }
  }
  float sv[8], dv[8];
#pragma unroll
  for (int h = 0; h < 8; h++){ sv[h] = att_s[h * 16 + l16]; dv[h] = att_d[h * 16 + l16]; }
#pragma unroll
  for (int r = 0; r < 4; r++){
    const int gr = m0 + wr0 + quad * 4 + r;
    float s[8], d[8];
#pragma unroll
    for (int h = 0; h < 8; h++){ s[h] = acc[h][r] * sv[h]; d[h] = acc[h][r] * dv[h]; }
#pragma unroll
    for (int o = 1; o < 16; o <<= 1){
#pragma unroll
      for (int h = 0; h < 8; h++){ s[h] += __shfl_xor(s[h], o); d[h] += __shfl_xor(d[h], o); }
    }
    if (gr < NN){
#pragma unroll
      for (int h = 0; h < 8; h++)
        h1b[(size_t)gr * HC + h * 16 + l16] = (unsigned short)f2bf(acc[h][r]);
      if (l16 == 0){
        *(float4*)(as1 + gr * 8)     = make_float4(s[0], s[1], s[2], s[3]);
        *(float4*)(as1 + gr * 8 + 4) = make_float4(s[4], s[5], s[6], s[7]);
        *(float4*)(ad1 + gr * 8)     = make_float4(d[0], d[1], d[2], d[3]);
        *(float4*)(ad1 + gr * 8 + 4) = make_float4(d[4], d[5], d[6], d[7]);
      }
    }
  }
}

// K2: layer-1 aggregate, TWO NODES PER WAVE. 4 waves/block = 8 nodes, NO barriers.
// Phase A (per node j): lane = (head, edge-slot); 3-step butterflies; weights+zeros
// to chunk count shared across the pair (tail guard-free). Phase B: lane =
// (node = lane>>5, 4 channels via uint2): each load instruction fetches TWO full
// 256B rows -> 2x data-MLP per wave, ~44% fewer load instructions per node.
__global__ __launch_bounds__(256) void k_agg1(const int* __restrict__ srcp,
                                              const int* __restrict__ cnt,
                                              const float* __restrict__ as1,
                                              const float* __restrict__ ad1,
                                              const unsigned short* __restrict__ h1b,
                                              const float* __restrict__ b1,
                                              unsigned short* __restrict__ h2b){
  __shared__ float wls[4][2][64][8];   // 16 KB [wave][node][edge][head]
  __shared__ int   sls[4][2][64];      // prescaled s<<5 (uint2 row base)
  __shared__ float dls[4][2][8];       // denominators per node per head
  const int lane = threadIdx.x & 63, w = threadIdx.x >> 6;
  const int nb = blockIdx.x * 8 + w * 2;
  const int h = lane >> 3, e8 = lane & 7;

  int degs[2], nEs[2];
#pragma unroll
  for (int j = 0; j < 2; j++){
    int d = cnt[nb + j]; if (d > CAP - 1) d = CAP - 1;
    degs[j] = d; nEs[j] = d + 1;
  }
  const int nEm = max(nEs[0], nEs[1]);
  int nCh = (nEm + 7) >> 3; if (nCh < 2) nCh = 2;   // shared -> both nodes zero-fill

#pragma unroll
  for (int j = 0; j < 2; j++){
    const int n = nb + j;
    const int deg = degs[j], nE = nEs[j];
    int sA = n;                                     // lanes >= deg hold self id
    if (lane < deg) sA = srcp[n * CAP + lane];      // coalesced row read
    sls[w][j][lane] = sA << 5;

    const float adg = ad1[n * 8 + h];
    float mx = -3.0e38f;
    for (int c = 0; c < nCh; c++){
      const int i = c * 8 + e8;
      const int s8 = sls[w][j][i] >> 2;             // == s*8
      const float v = (i < nE) ? leaky(as1[(size_t)(unsigned)(s8 + h)] + adg) : -3.0e38f;
      wls[w][j][i][h] = v;
      mx = fmaxf(mx, v);
    }
    mx = fmaxf(mx, __shfl_xor(mx, 1));
    mx = fmaxf(mx, __shfl_xor(mx, 2));
    mx = fmaxf(mx, __shfl_xor(mx, 4));

    float den = 0.f;
    for (int c = 0; c < nCh; c++){
      const int i = c * 8 + e8;
      const float v = wls[w][j][i][h];
      const float wt = (i < nE) ? __expf(v - mx) : 0.f;
      wls[w][j][i][h] = wt;                         // zeros out to nCh*8 >= nEm
      den += wt;
    }
    den += __shfl_xor(den, 1);
    den += __shfl_xor(den, 2);
    den += __shfl_xor(den, 4);
    if (e8 == 0) dls[w][j][h] = den;
  }

  // Phase B: node j = lane>>5; l32 = lane&31 -> channels 4*l32..4*l32+3 (head l32>>2).
  const int j = lane >> 5, l32 = lane & 31, hb = l32 >> 2;
  const uint2* hp = (const uint2*)h1b;
  float a0 = 0.f, a1 = 0.f, a2 = 0.f, a3 = 0.f;
  {
    uint2 u[16]; float q[16];
#pragma unroll
    for (int i = 0; i < 16; i++){
      u[i] = hp[(size_t)(unsigned)(sls[w][j][i] + l32)];
      q[i] = wls[w][j][i][hb];                      // ==0 beyond nE (nCh>=2 covers 16)
    }
#pragma unroll
    for (int i = 0; i < 16; i++){
      a0 += q[i] * bflo(u[i].x); a1 += q[i] * bfhi(u[i].x);
      a2 += q[i] * bflo(u[i].y); a3 += q[i] * bfhi(u[i].y);
    }
  }
  for (int i0 = 16; i0 < nEm; i0 += 8){             // wave-uniform; i < nCh*8 always
    uint2 uu[8]; float qq[8];
#pragma unroll
    for (int t = 0; t < 8; t++){
      const int i = i0 + t;
      uu[t] = hp[(size_t)(unsigned)(sls[w][j][i] + l32)];
      qq[t] = wls[w][j][i][hb];
    }
#pragma unroll
    for (int t = 0; t < 8; t++){
      a0 += qq[t] * bflo(uu[t].x); a1 += qq[t] * bfhi(uu[t].x);
      a2 += qq[t] * bflo(uu[t].y); a3 += qq[t] * bfhi(uu[t].y);
    }
  }

  const int n = nb + j;
  const float invd = 1.f / (dls[w][j][hb] + 1e-16f);
  const float4 bb = *(const float4*)(b1 + 4 * l32);
  float o0 = a0 * invd + bb.x;
  float o1 = a1 * invd + bb.y;
  float o2 = a2 * invd + bb.z;
  float o3 = a3 * invd + bb.w;
  o0 = o0 > 0.f ? o0 : (__expf(o0) - 1.f);          // ELU
  o1 = o1 > 0.f ? o1 : (__expf(o1) - 1.f);
  o2 = o2 > 0.f ? o2 : (__expf(o2) - 1.f);
  o3 = o3 > 0.f ? o3 : (__expf(o3) - 1.f);
  uint2 pk; pk.x = pack2bf(o0, o1); pk.y = pack2bf(o2, o3);
  ((uint2*)h2b)[(size_t)n * 32 + l32] = pk;
}

// K3: MFMA GEMM g(bf16)[N,40] = h2(bf16) @ W2 (N padded to 48), async-LDS staging
// of h2 rows (source-swizzled), fused att2 dots. Barrier-free.
__global__ __launch_bounds__(256, 3) void k_gemm2(const unsigned short* __restrict__ h2b,
                                                  const uint4* __restrict__ W2bfs,
                                                  const float* __restrict__ att_s2,
                                                  const float* __restrict__ att_d2,
                                                  unsigned short* __restrict__ gb,
                                                  float* __restrict__ as2,
                                                  float* __restrict__ ad2){
  __shared__ unsigned short h2s[BM2 * HC];   // 16 KB
  const int tid = threadIdx.x;
  const int wave = tid >> 6, lane = tid & 63;
  const int quad = lane >> 4, l16 = lane & 15;
  const int m0 = blockIdx.x * BM2;
  const int wr0 = wave * 16;

#pragma unroll
  for (int i = 0; i < 4; i++){
    const int rl = i * 4 + (lane >> 4);   // local row 0..15
    int grow = m0 + wr0 + rl; if (grow >= NN) grow = NN - 1;
    const int g = lane & 15;
    const unsigned short* src = h2b + (size_t)grow * HC + ((g ^ (rl & 7)) << 3);
    gld_lds16(src, &h2s[(wr0 + i * 4) * HC]);
  }

  FragU b2f[12];
#pragma unroll
  for (int f = 0; f < 12; f++) b2f[f].u = W2bfs[f * 64 + lane];

  asm volatile("s_waitcnt vmcnt(0)" ::: "memory");
  __builtin_amdgcn_sched_barrier(0);

  f32x4 acc[3];
#pragma unroll
  for (int t = 0; t < 3; t++) acc[t] = (f32x4){0.f, 0.f, 0.f, 0.f};

  const int swz = l16 & 7;
  const unsigned short* hrow = &h2s[(wr0 + l16) * HC];
#pragma unroll
  for (int kt = 0; kt < 4; kt++){
    FragU af;
    af.u = *(const uint4*)(hrow + (((kt * 4 + quad) ^ swz) << 3));
#pragma unroll
    for (int nt = 0; nt < 3; nt++)
      acc[nt] = __builtin_amdgcn_mfma_f32_16x16x32_bf16(af.s, b2f[kt * 3 + nt].s, acc[nt], 0, 0, 0);
  }

  float sv[3], dv[3];
#pragma unroll
  for (int nt = 0; nt < 3; nt++){
    const int c = nt * 16 + l16;
    sv[nt] = (c < NC) ? att_s2[c] : 0.f;
    dv[nt] = (c < NC) ? att_d2[c] : 0.f;
  }
#pragma unroll
  for (int r = 0; r < 4; r++){
    const int gr = m0 + wr0 + quad * 4 + r;
    float s = acc[0][r] * sv[0] + acc[1][r] * sv[1] + acc[2][r] * sv[2];
    float d = acc[0][r] * dv[0] + acc[1][r] * dv[1] + acc[2][r] * dv[2];
#pragma unroll
    for (int o = 1; o < 16; o <<= 1){ s += __shfl_xor(s, o); d += __shfl_xor(d, o); }
    if (gr < NN){
#pragma unroll
      for (int nt = 0; nt < 3; nt++){
        const int c = nt * 16 + l16;
        if (c < NC) gb[(size_t)gr * NC + c] = (unsigned short)f2bf(acc[nt][r]);
      }
      if (l16 == 0){ as2[gr] = s; ad2[gr] = d; }
    }
  }
}

// K4: layer-2 aggregate, two-phase lane-parallel softmax + log_softmax. One wave
// per node, 8 nodes / 512-thread block, NO barriers. sls pre-scaled (s*NC).
__global__ __launch_bounds__(512) void k_agg2(const int* __restrict__ srcp,
                                              const int* __restrict__ cnt,
                                              const float* __restrict__ as2,
                                              const float* __restrict__ ad2,
                                              const unsigned short* __restrict__ gb,
                                              const float* __restrict__ b2,
                                              float* __restrict__ out){
  __shared__ float wls[8][64];
  __shared__ int   sls[8][64];
  const int lane = threadIdx.x & 63, w = threadIdx.x >> 6;
  const int n = blockIdx.x * 8 + w;
  int deg = cnt[n]; if (deg > CAP - 1) deg = CAP - 1;
  const int nE = deg + 1;
  const bool act = (lane <= deg);
  int sA = n;
  if (lane < deg) sA = srcp[n * CAP + lane];
  const float ad = ad2[n];
  float v = act ? leaky(as2[sA] + ad) : -3.0e38f;
  sls[w][lane] = sA * NC;
  float mx = v;
#pragma unroll
  for (int o = 1; o < 64; o <<= 1) mx = fmaxf(mx, __shfl_xor(mx, o));
  float wt = act ? __expf(v - mx) : 0.f;
  float den = wt;
#pragma unroll
  for (int o = 1; o < 64; o <<= 1) den += __shfl_xor(den, o);
  wls[w][lane] = wt;

  const int c = min(lane, NC - 1);
  float acc = 0.f;
  {
    float g[16], q[16];
#pragma unroll
    for (int i = 0; i < 16; i++){
      g[i] = bfus(gb[(size_t)(unsigned)(sls[w][i] + c)]);
      q[i] = wls[w][i];
    }
#pragma unroll
    for (int i = 0; i < 16; i++) acc += q[i] * g[i];
  }
  for (int i0 = 16; i0 < nE; i0 += 8){
    float gg[8], qq[8];
#pragma unroll
    for (int t = 0; t < 8; t++){
      const int j = i0 + t;
      gg[t] = bfus(gb[(size_t)(unsigned)(sls[w][j] + c)]);
      qq[t] = wls[w][j];
    }
#pragma unroll
    for (int t = 0; t < 8; t++) acc += qq[t] * gg[t];
  }
  const float invd = 1.f / (den + 1e-16f);
  const bool cl = (lane < NC);
  float f = acc * invd + b2[c];
  if (cl) out[(size_t)n * NC + lane] = f;
  float fv = cl ? f : -3.4e38f;
  float m2 = fv;
#pragma unroll
  for (int o = 1; o < 64; o <<= 1) m2 = fmaxf(m2, __shfl_xor(m2, o));
  float ex = cl ? __expf(fv - m2) : 0.f;
#pragma unroll
  for (int o = 1; o < 64; o <<= 1) ex += __shfl_xor(ex, o);
  const float lse = m2 + __logf(ex);
  if (cl) out[(size_t)(NN * NC) + (size_t)n * NC + lane] = fv - lse;
}

extern "C" void kernel_launch(void* const* d_in, const int* in_sizes, int n_in,
                              void* d_out, int out_size, void* d_ws, size_t ws_size,
                              hipStream_t stream){
  const float* x      = (const float*)d_in[0];
  const int*   ei     = (const int*)  d_in[1];
  const float* W1     = (const float*)d_in[3];
  const float* att_s1 = (const float*)d_in[4];
  const float* att_d1 = (const float*)d_in[5];
  const float* b1     = (const float*)d_in[6];
  const float* W2     = (const float*)d_in[7];
  const float* att_s2 = (const float*)d_in[8];
  const float* att_d2 = (const float*)d_in[9];
  const float* b2     = (const float*)d_in[10];
  float* out = (float*)d_out;

  char* wp = (char*)d_ws;
  uint4* W1bfs = (uint4*)wp;                 wp += (size_t)4096 * 16;      // 64 KB
  uint4* W2bfs = (uint4*)wp;                 wp += (size_t)768 * 16;       // 12 KB
  unsigned short* h1b = (unsigned short*)wp; wp += (size_t)NN * HC * 2;    // 12.8 MB
  unsigned short* h2b = (unsigned short*)wp; wp += (size_t)NN * HC * 2;    // 12.8 MB
  unsigned short* gb  = (unsigned short*)wp; wp += (size_t)NN * NC * 2;    // 4 MB
  float* as1 = (float*)wp;                   wp += (size_t)NN * HD * 4;
  float* ad1 = (float*)wp;                   wp += (size_t)NN * HD * 4;
  float* as2 = (float*)wp;                   wp += (size_t)NN * 4;
  float* ad2 = (float*)wp;                   wp += (size_t)NN * 4;
  int* cnt   = (int*)wp;                     wp += (size_t)NN * 4;
  int* srcp  = (int*)wp;                     wp += (size_t)NN * CAP * 4;   // 12.8 MB
  uint4* xb  = (uint4*)wp;                   wp += (size_t)NN * FIN * 2;   // 25.6 MB (bf16 x)

  const bool usebf = ws_size >= (size_t)(wp - (char*)d_ws);
  const int convb = usebf ? CONVB : 0;

  hipMemsetAsync(cnt, 0, (size_t)NN * sizeof(int), stream);
  k_prep <<<PREPB + convb + SCB, 256, 0, stream>>>(W1, W1bfs, W2, W2bfs, x, xb, convb,
                                                   ei, cnt, srcp);
  if (usebf)
    k_gemm1b <<<GB1, 256, 0, stream>>>((const unsigned short*)xb, W1bfs, att_s1, att_d1,
                                       h1b, as1, ad1);
  else
    k_gemm1f <<<GB1, 256, 0, stream>>>(x, W1bfs, att_s1, att_d1, h1b, as1, ad1);
  k_agg1  <<<NN / 8, 256, 0, stream>>>(srcp, cnt, as1, ad1, h1b, b1, h2b);
  k_gemm2 <<<(NN + BM2 - 1) / BM2, 256, 0, stream>>>(h2b, W2bfs, att_s2, att_d2, gb, as2, ad2);
  k_agg2  <<<NN / 8, 512, 0, stream>>>(srcp, cnt, as2, ad2, gb, b2, out);
}

// Round 9
// 235.670 us; speedup vs baseline: 1.0200x; 1.0200x over previous
//
#include <hip/hip_runtime.h>

#define NN 50000
#define EE 800000
#define FIN 256
#define HD 8
#define C1 16
#define HC 128         // HD*C1
#define NC 40
#define NEG 0.2f
#define CAP 64         // ELL capacity per node; P(Poisson(16) >= 64) ~ 1e-17
#define BM 64          // gemm1 row tile (4 waves x 16 rows)
#define BM2 64         // gemm2 row tile
#define GB1 ((NN + BM - 1) / BM)  // 782 blocks
#define NP_N (NN / 8)  // nodes per partition (6250)
#define SCB 2048       // scatter blocks (8 partitions x 256 ranks), FIRST in k_prep
#define PREPB 19       // 16 W1-swizzle blocks + 3 W2-swizzle blocks, after scatter

typedef __attribute__((ext_vector_type(8))) short short8;   // 8 bf16 (4 VGPRs)
typedef __attribute__((ext_vector_type(4))) float f32x4;    // MFMA C/D
union FragU { uint4 u; short8 s; };

__device__ __forceinline__ float leaky(float v){ return v > 0.f ? v : NEG * v; }

// fp32 -> bf16 round-to-nearest-even (no NaNs in this workload)
__device__ __forceinline__ unsigned int f2bf(float f){
  unsigned int u = __float_as_uint(f);
  u += 0x7fffu + ((u >> 16) & 1u);
  return u >> 16;
}
__device__ __forceinline__ unsigned int pack2bf(float a, float b){
  return f2bf(a) | (f2bf(b) << 16);
}
__device__ __forceinline__ float bflo(unsigned int u){ return __uint_as_float(u << 16); }
__device__ __forceinline__ float bfhi(unsigned int u){ return __uint_as_float(u & 0xffff0000u); }
__device__ __forceinline__ float bfus(unsigned short u){ return __uint_as_float((unsigned int)u << 16); }

// async 16B global->LDS (DMA, no VGPR round-trip). LDS dest = uniform base + lane*16.
__device__ __forceinline__ void gld_lds16(const void* g, void* l){
  __builtin_amdgcn_global_load_lds((const __attribute__((address_space(1))) unsigned int*)g,
                                   (__attribute__((address_space(3))) unsigned int*)l,
                                   16, 0, 0);
}

// K0: blocks 0..SCB-1 = XCD-partitioned ELL scatter, TWO edges per lane per
// iteration (int2 dst reads halve the dependent chain, double atomic MLP).
// Blocks SCB.. = W1/W2 MFMA-fragment prep (tiny, backfills behind the scatter).
__global__ __launch_bounds__(256) void k_prep(const float* __restrict__ W1,
                                              uint4* __restrict__ W1bfs,
                                              const float* __restrict__ W2,
                                              uint4* __restrict__ W2bfs,
                                              const int* __restrict__ ei,
                                              int* __restrict__ cnt,
                                              int* __restrict__ srcp){
  const int tid = threadIdx.x;
  if (blockIdx.x < SCB){
    const int part = blockIdx.x & 7, rank = blockIdx.x >> 3;   // b&7 == XCD (round-robin)
    const int lo = part * NP_N, hi = lo + NP_N;
    const int2* dp = (const int2*)(ei + EE);                   // dst pairs, 8B-aligned
    for (int e2 = rank * 256 + tid; e2 < EE / 2; e2 += 256 * 256){
      const int2 d2 = dp[e2];
      if (d2.x >= lo && d2.x < hi){
        int s = ei[2 * e2];
        int pos = atomicAdd(&cnt[d2.x], 1);
        if (pos < CAP) srcp[d2.x * CAP + pos] = s;   // clamp guard (never hit per Poisson tail)
      }
      if (d2.y >= lo && d2.y < hi){
        int s = ei[2 * e2 + 1];
        int pos = atomicAdd(&cnt[d2.y], 1);
        if (pos < CAP) srcp[d2.y * CAP + pos] = s;
      }
    }
    return;
  }
  const int pb = blockIdx.x - SCB;
  if (pb < 16){   // W1 (fp32 [256][128]) -> MFMA B-fragments (bf16)
    int f = pb * 256 + tid;   // 0..4095
    int lane = f & 63, nt = (f >> 6) & 7, kt = f >> 9;
    int quad = lane >> 4, l16 = lane & 15;
    const float* src = W1 + (size_t)(kt * 32 + quad * 8) * HC + nt * 16 + l16;
    unsigned int p[4];
#pragma unroll
    for (int jj = 0; jj < 4; jj++)
      p[jj] = pack2bf(src[(size_t)(2 * jj) * HC], src[(size_t)(2 * jj + 1) * HC]);
    W1bfs[f] = make_uint4(p[0], p[1], p[2], p[3]);
    return;
  }
  // W2 (fp32 [128][40]) -> MFMA B-fragments, N padded to 48 (3 nt tiles)
  int f = (pb - 16) * 256 + tid;   // 0..767 = 12 fragments x 64 lanes
  int lane = f & 63, frag = f >> 6;        // frag = kt*3 + nt
  int kt = frag / 3, nt = frag - kt * 3;
  int quad = lane >> 4, l16 = lane & 15;
  int n = nt * 16 + l16;                   // output col, pad >= NC with zeros
  int k0 = kt * 32 + quad * 8;
  unsigned int p[4];
#pragma unroll
  for (int jj = 0; jj < 4; jj++){
    float v0 = (n < NC) ? W2[(size_t)(k0 + 2 * jj) * NC + n] : 0.f;
    float v1 = (n < NC) ? W2[(size_t)(k0 + 2 * jj + 1) * NC + n] : 0.f;
    p[jj] = pack2bf(v0, v1);
  }
  W2bfs[f] = make_uint4(p[0], p[1], p[2], p[3]);
}

// K1: async-LDS GEMM h1(bf16)[N,128] = x @ W1, bf16 MFMA 16x16x32, BARRIER-FREE.
// Each wave stages its OWN 16 x-rows via 16 global_load_lds (zero VGPR, all async),
// one vmcnt(0), then MFMA from LDS. Source granules pre-swizzled (g ^ (row&7)) so
// the linear DMA write yields 32-bank-spread ds_read_b128.
__global__ __launch_bounds__(256, 2) void k_gemm1(const float* __restrict__ x,
                                                  const uint4* __restrict__ W1bfs,
                                                  const float* __restrict__ att_s,
                                                  const float* __restrict__ att_d,
                                                  unsigned short* __restrict__ h1b,
                                                  float* __restrict__ as1,
                                                  float* __restrict__ ad1){
  __shared__ float xs[BM * FIN];   // 64 KB; wave w owns rows [w*16, w*16+16)
  const int tid = threadIdx.x;
  const int wave = tid >> 6, lane = tid & 63;
  const int quad = lane >> 4, l16 = lane & 15;
  const int m0 = blockIdx.x * BM;
  const int wr0 = wave * 16;

#pragma unroll
  for (int i = 0; i < 16; i++){
    int grow = m0 + wr0 + i; if (grow >= NN) grow = NN - 1;   // clamp (dup stage benign)
    const float* src = x + (size_t)grow * FIN + ((lane ^ (i & 7)) << 2);
    gld_lds16(src, &xs[(wr0 + i) * FIN]);
  }

  FragU bf[8];
#pragma unroll
  for (int nt = 0; nt < 8; nt++) bf[nt].u = W1bfs[nt * 64 + lane];

  asm volatile("s_waitcnt vmcnt(0)" ::: "memory");
  __builtin_amdgcn_sched_barrier(0);

  f32x4 acc[8];
#pragma unroll
  for (int t = 0; t < 8; t++) acc[t] = (f32x4){0.f, 0.f, 0.f, 0.f};

  const int swz = l16 & 7;
  const float* xrow = &xs[(wr0 + l16) * FIN];
#pragma unroll
  for (int kt = 0; kt < 8; kt++){
    FragU bn[8];
    if (kt < 7){
#pragma unroll
      for (int nt = 0; nt < 8; nt++)
        bn[nt].u = W1bfs[((kt + 1) * 8 + nt) * 64 + lane];
    }
    const int g0 = kt * 8 + quad * 2;
    const float4 a0 = *(const float4*)(xrow + ((g0 ^ swz) << 2));
    const float4 a1 = *(const float4*)(xrow + (((g0 + 1) ^ swz) << 2));
    FragU af;
    af.u = make_uint4(pack2bf(a0.x, a0.y), pack2bf(a0.z, a0.w),
                      pack2bf(a1.x, a1.y), pack2bf(a1.z, a1.w));
#pragma unroll
    for (int nt = 0; nt < 8; nt++)
      acc[nt] = __builtin_amdgcn_mfma_f32_16x16x32_bf16(af.s, bf[nt].s, acc[nt], 0, 0, 0);
    if (kt < 7){
#pragma unroll
      for (int nt = 0; nt < 8; nt++) bf[nt] = bn[nt];
    }
  }

  float sv[8], dv[8];
#pragma unroll
  for (int h = 0; h < 8; h++){ sv[h] = att_s[h * 16 + l16]; dv[h] = att_d[h * 16 + l16]; }
#pragma unroll
  for (int r = 0; r < 4; r++){
    const int gr = m0 + wr0 + quad * 4 + r;
    float s[8], d[8];
#pragma unroll
    for (int h = 0; h < 8; h++){ s[h] = acc[h][r] * sv[h]; d[h] = acc[h][r] * dv[h]; }
#pragma unroll
    for (int o = 1; o < 16; o <<= 1){
#pragma unroll
      for (int h = 0; h < 8; h++){ s[h] += __shfl_xor(s[h], o); d[h] += __shfl_xor(d[h], o); }
    }
    if (gr < NN){
#pragma unroll
      for (int h = 0; h < 8; h++)
        h1b[(size_t)gr * HC + h * 16 + l16] = (unsigned short)f2bf(acc[h][r]);
      if (l16 == 0){
        *(float4*)(as1 + gr * 8)     = make_float4(s[0], s[1], s[2], s[3]);
        *(float4*)(as1 + gr * 8 + 4) = make_float4(s[4], s[5], s[6], s[7]);
        *(float4*)(ad1 + gr * 8)     = make_float4(d[0], d[1], d[2], d[3]);
        *(float4*)(ad1 + gr * 8 + 4) = make_float4(d[4], d[5], d[6], d[7]);
      }
    }
  }
}

// K2: layer-1 aggregate, TWO NODES PER WAVE. 4 waves/block = 8 nodes, NO barriers.
// Phase A (per node j): lane = (head, edge-slot); 3-step butterflies. Phase B:
// lane = (node = lane>>5, 4 channels via uint2): each load fetches TWO full 256B
// rows -> 2x data-MLP per wave.
__global__ __launch_bounds__(256) void k_agg1(const int* __restrict__ srcp,
                                              const int* __restrict__ cnt,
                                              const float* __restrict__ as1,
                                              const float* __restrict__ ad1,
                                              const unsigned short* __restrict__ h1b,
                                              const float* __restrict__ b1,
                                              unsigned short* __restrict__ h2b){
  __shared__ float wls[4][2][64][8];   // 16 KB [wave][node][edge][head]
  __shared__ int   sls[4][2][64];      // prescaled s<<5 (uint2 row base)
  __shared__ float dls[4][2][8];       // denominators per node per head
  const int lane = threadIdx.x & 63, w = threadIdx.x >> 6;
  const int nb = blockIdx.x * 8 + w * 2;
  const int h = lane >> 3, e8 = lane & 7;

  int degs[2], nEs[2];
#pragma unroll
  for (int j = 0; j < 2; j++){
    int d = cnt[nb + j]; if (d > CAP - 1) d = CAP - 1;
    degs[j] = d; nEs[j] = d + 1;
  }
  const int nEm = max(nEs[0], nEs[1]);
  int nCh = (nEm + 7) >> 3; if (nCh < 2) nCh = 2;   // shared -> both nodes zero-fill

#pragma unroll
  for (int j = 0; j < 2; j++){
    const int n = nb + j;
    const int deg = degs[j], nE = nEs[j];
    int sA = n;                                     // lanes >= deg hold self id
    if (lane < deg) sA = srcp[n * CAP + lane];      // coalesced row read
    sls[w][j][lane] = sA << 5;

    const float adg = ad1[n * 8 + h];
    float mx = -3.0e38f;
    for (int c = 0; c < nCh; c++){
      const int i = c * 8 + e8;
      const int s8 = sls[w][j][i] >> 2;             // == s*8
      const float v = (i < nE) ? leaky(as1[(size_t)(unsigned)(s8 + h)] + adg) : -3.0e38f;
      wls[w][j][i][h] = v;
      mx = fmaxf(mx, v);
    }
    mx = fmaxf(mx, __shfl_xor(mx, 1));
    mx = fmaxf(mx, __shfl_xor(mx, 2));
    mx = fmaxf(mx, __shfl_xor(mx, 4));

    float den = 0.f;
    for (int c = 0; c < nCh; c++){
      const int i = c * 8 + e8;
      const float v = wls[w][j][i][h];
      const float wt = (i < nE) ? __expf(v - mx) : 0.f;
      wls[w][j][i][h] = wt;                         // zeros out to nCh*8 >= nEm
      den += wt;
    }
    den += __shfl_xor(den, 1);
    den += __shfl_xor(den, 2);
    den += __shfl_xor(den, 4);
    if (e8 == 0) dls[w][j][h] = den;
  }

  // Phase B: node j = lane>>5; l32 = lane&31 -> channels 4*l32..4*l32+3 (head l32>>2).
  const int j = lane >> 5, l32 = lane & 31, hb = l32 >> 2;
  const uint2* hp = (const uint2*)h1b;
  float a0 = 0.f, a1 = 0.f, a2 = 0.f, a3 = 0.f;
  {
    uint2 u[16]; float q[16];
#pragma unroll
    for (int i = 0; i < 16; i++){
      u[i] = hp[(size_t)(unsigned)(sls[w][j][i] + l32)];
      q[i] = wls[w][j][i][hb];                      // ==0 beyond nE (nCh>=2 covers 16)
    }
#pragma unroll
    for (int i = 0; i < 16; i++){
      a0 += q[i] * bflo(u[i].x); a1 += q[i] * bfhi(u[i].x);
      a2 += q[i] * bflo(u[i].y); a3 += q[i] * bfhi(u[i].y);
    }
  }
  for (int i0 = 16; i0 < nEm; i0 += 8){             // wave-uniform; i < nCh*8 always
    uint2 uu[8]; float qq[8];
#pragma unroll
    for (int t = 0; t < 8; t++){
      const int i = i0 + t;
      uu[t] = hp[(size_t)(unsigned)(sls[w][j][i] + l32)];
      qq[t] = wls[w][j][i][hb];
    }
#pragma unroll
    for (int t = 0; t < 8; t++){
      a0 += qq[t] * bflo(uu[t].x); a1 += qq[t] * bfhi(uu[t].x);
      a2 += qq[t] * bflo(uu[t].y); a3 += qq[t] * bfhi(uu[t].y);
    }
  }

  const int n = nb + j;
  const float invd = 1.f / (dls[w][j][hb] + 1e-16f);
  const float4 bb = *(const float4*)(b1 + 4 * l32);
  float o0 = a0 * invd + bb.x;
  float o1 = a1 * invd + bb.y;
  float o2 = a2 * invd + bb.z;
  float o3 = a3 * invd + bb.w;
  o0 = o0 > 0.f ? o0 : (__expf(o0) - 1.f);          // ELU
  o1 = o1 > 0.f ? o1 : (__expf(o1) - 1.f);
  o2 = o2 > 0.f ? o2 : (__expf(o2) - 1.f);
  o3 = o3 > 0.f ? o3 : (__expf(o3) - 1.f);
  uint2 pk; pk.x = pack2bf(o0, o1); pk.y = pack2bf(o2, o3);
  ((uint2*)h2b)[(size_t)n * 32 + l32] = pk;
}

// K3: MFMA GEMM g(bf16)[N,40] = h2(bf16) @ W2 (N padded to 48), async-LDS staging
// of h2 rows (source-swizzled), fused att2 dots. Barrier-free.
__global__ __launch_bounds__(256, 3) void k_gemm2(const unsigned short* __restrict__ h2b,
                                                  const uint4* __restrict__ W2bfs,
                                                  const float* __restrict__ att_s2,
                                                  const float* __restrict__ att_d2,
                                                  unsigned short* __restrict__ gb,
                                                  float* __restrict__ as2,
                                                  float* __restrict__ ad2){
  __shared__ unsigned short h2s[BM2 * HC];   // 16 KB
  const int tid = threadIdx.x;
  const int wave = tid >> 6, lane = tid & 63;
  const int quad = lane >> 4, l16 = lane & 15;
  const int m0 = blockIdx.x * BM2;
  const int wr0 = wave * 16;

#pragma unroll
  for (int i = 0; i < 4; i++){
    const int rl = i * 4 + (lane >> 4);   // local row 0..15
    int grow = m0 + wr0 + rl; if (grow >= NN) grow = NN - 1;
    const int g = lane & 15;
    const unsigned short* src = h2b + (size_t)grow * HC + ((g ^ (rl & 7)) << 3);
    gld_lds16(src, &h2s[(wr0 + i * 4) * HC]);
  }

  FragU b2f[12];
#pragma unroll
  for (int f = 0; f < 12; f++) b2f[f].u = W2bfs[f * 64 + lane];

  asm volatile("s_waitcnt vmcnt(0)" ::: "memory");
  __builtin_amdgcn_sched_barrier(0);

  f32x4 acc[3];
#pragma unroll
  for (int t = 0; t < 3; t++) acc[t] = (f32x4){0.f, 0.f, 0.f, 0.f};

  const int swz = l16 & 7;
  const unsigned short* hrow = &h2s[(wr0 + l16) * HC];
#pragma unroll
  for (int kt = 0; kt < 4; kt++){
    FragU af;
    af.u = *(const uint4*)(hrow + (((kt * 4 + quad) ^ swz) << 3));
#pragma unroll
    for (int nt = 0; nt < 3; nt++)
      acc[nt] = __builtin_amdgcn_mfma_f32_16x16x32_bf16(af.s, b2f[kt * 3 + nt].s, acc[nt], 0, 0, 0);
  }

  float sv[3], dv[3];
#pragma unroll
  for (int nt = 0; nt < 3; nt++){
    const int c = nt * 16 + l16;
    sv[nt] = (c < NC) ? att_s2[c] : 0.f;
    dv[nt] = (c < NC) ? att_d2[c] : 0.f;
  }
#pragma unroll
  for (int r = 0; r < 4; r++){
    const int gr = m0 + wr0 + quad * 4 + r;
    float s = acc[0][r] * sv[0] + acc[1][r] * sv[1] + acc[2][r] * sv[2];
    float d = acc[0][r] * dv[0] + acc[1][r] * dv[1] + acc[2][r] * dv[2];
#pragma unroll
    for (int o = 1; o < 16; o <<= 1){ s += __shfl_xor(s, o); d += __shfl_xor(d, o); }
    if (gr < NN){
#pragma unroll
      for (int nt = 0; nt < 3; nt++){
        const int c = nt * 16 + l16;
        if (c < NC) gb[(size_t)gr * NC + c] = (unsigned short)f2bf(acc[nt][r]);
      }
      if (l16 == 0){ as2[gr] = s; ad2[gr] = d; }
    }
  }
}

// K4: layer-2 aggregate, two-phase lane-parallel softmax + log_softmax. One wave
// per node, 8 nodes / 512-thread block, NO barriers. sls pre-scaled (s*NC).
__global__ __launch_bounds__(512) void k_agg2(const int* __restrict__ srcp,
                                              const int* __restrict__ cnt,
                                              const float* __restrict__ as2,
                                              const float* __restrict__ ad2,
                                              const unsigned short* __restrict__ gb,
                                              const float* __restrict__ b2,
                                              float* __restrict__ out){
  __shared__ float wls[8][64];
  __shared__ int   sls[8][64];
  const int lane = threadIdx.x & 63, w = threadIdx.x >> 6;
  const int n = blockIdx.x * 8 + w;
  int deg = cnt[n]; if (deg > CAP - 1) deg = CAP - 1;
  const int nE = deg + 1;
  const bool act = (lane <= deg);
  int sA = n;
  if (lane < deg) sA = srcp[n * CAP + lane];
  const float ad = ad2[n];
  float v = act ? leaky(as2[sA] + ad) : -3.0e38f;
  sls[w][lane] = sA * NC;
  float mx = v;
#pragma unroll
  for (int o = 1; o < 64; o <<= 1) mx = fmaxf(mx, __shfl_xor(mx, o));
  float wt = act ? __expf(v - mx) : 0.f;
  float den = wt;
#pragma unroll
  for (int o = 1; o < 64; o <<= 1) den += __shfl_xor(den, o);
  wls[w][lane] = wt;

  const int c = min(lane, NC - 1);
  float acc = 0.f;
  {
    float g[16], q[16];
#pragma unroll
    for (int i = 0; i < 16; i++){
      g[i] = bfus(gb[(size_t)(unsigned)(sls[w][i] + c)]);
      q[i] = wls[w][i];
    }
#pragma unroll
    for (int i = 0; i < 16; i++) acc += q[i] * g[i];
  }
  for (int i0 = 16; i0 < nE; i0 += 8){
    float gg[8], qq[8];
#pragma unroll
    for (int t = 0; t < 8; t++){
      const int j = i0 + t;
      gg[t] = bfus(gb[(size_t)(unsigned)(sls[w][j] + c)]);
      qq[t] = wls[w][j];
    }
#pragma unroll
    for (int t = 0; t < 8; t++) acc += qq[t] * gg[t];
  }
  const float invd = 1.f / (den + 1e-16f);
  const bool cl = (lane < NC);
  float f = acc * invd + b2[c];
  if (cl) out[(size_t)n * NC + lane] = f;
  float fv = cl ? f : -3.4e38f;
  float m2 = fv;
#pragma unroll
  for (int o = 1; o < 64; o <<= 1) m2 = fmaxf(m2, __shfl_xor(m2, o));
  float ex = cl ? __expf(fv - m2) : 0.f;
#pragma unroll
  for (int o = 1; o < 64; o <<= 1) ex += __shfl_xor(ex, o);
  const float lse = m2 + __logf(ex);
  if (cl) out[(size_t)(NN * NC) + (size_t)n * NC + lane] = fv - lse;
}

extern "C" void kernel_launch(void* const* d_in, const int* in_sizes, int n_in,
                              void* d_out, int out_size, void* d_ws, size_t ws_size,
                              hipStream_t stream){
  const float* x      = (const float*)d_in[0];
  const int*   ei     = (const int*)  d_in[1];
  const float* W1     = (const float*)d_in[3];
  const float* att_s1 = (const float*)d_in[4];
  const float* att_d1 = (const float*)d_in[5];
  const float* b1     = (const float*)d_in[6];
  const float* W2     = (const float*)d_in[7];
  const float* att_s2 = (const float*)d_in[8];
  const float* att_d2 = (const float*)d_in[9];
  const float* b2     = (const float*)d_in[10];
  float* out = (float*)d_out;

  char* wp = (char*)d_ws;
  uint4* W1bfs = (uint4*)wp;                 wp += (size_t)4096 * 16;      // 64 KB
  uint4* W2bfs = (uint4*)wp;                 wp += (size_t)768 * 16;       // 12 KB
  unsigned short* h1b = (unsigned short*)wp; wp += (size_t)NN * HC * 2;    // 12.8 MB
  unsigned short* h2b = (unsigned short*)wp; wp += (size_t)NN * HC * 2;    // 12.8 MB
  unsigned short* gb  = (unsigned short*)wp; wp += (size_t)NN * NC * 2;    // 4 MB
  float* as1 = (float*)wp;                   wp += (size_t)NN * HD * 4;
  float* ad1 = (float*)wp;                   wp += (size_t)NN * HD * 4;
  float* as2 = (float*)wp;                   wp += (size_t)NN * 4;
  float* ad2 = (float*)wp;                   wp += (size_t)NN * 4;
  int* cnt   = (int*)wp;                     wp += (size_t)NN * 4;
  int* srcp  = (int*)wp;                     wp += (size_t)NN * CAP * 4;   // 12.8 MB

  hipMemsetAsync(cnt, 0, (size_t)NN * sizeof(int), stream);
  k_prep  <<<SCB + PREPB, 256, 0, stream>>>(W1, W1bfs, W2, W2bfs, ei, cnt, srcp);
  k_gemm1 <<<GB1, 256, 0, stream>>>(x, W1bfs, att_s1, att_d1, h1b, as1, ad1);
  k_agg1  <<<NN / 8, 256, 0, stream>>>(srcp, cnt, as1, ad1, h1b, b1, h2b);
  k_gemm2 <<<(NN + BM2 - 1) / BM2, 256, 0, stream>>>(h2b, W2bfs, att_s2, att_d2, gb, as2, ad2);
  k_agg2  <<<NN / 8, 512, 0, stream>>>(srcp, cnt, as2, ad2, gb, b2, out);
}

// Round 11
// 233.276 us; speedup vs baseline: 1.0305x; 1.0103x over previous
//
#include <hip/hip_runtime.h>

#define NN 50000
#define EE 800000
#define FIN 256
#define HD 8
#define C1 16
#define HC 128         // HD*C1
#define NC 40
#define NEG 0.2f
#define CAP 64         // ELL capacity per node; P(Poisson(16) >= 64) ~ 1e-17
#define BM 64          // gemm1 row tile (4 waves x 16 rows)
#define BM2 64         // gemm2 row tile
#define GB1 ((NN + BM - 1) / BM)  // 782 blocks
#define NP_N (NN / 8)  // nodes per partition (6250)
#define SCB 2048       // scatter blocks (8 partitions x 256 ranks), FIRST in k_prep
#define PREPB 19       // 16 W1-swizzle blocks + 3 W2-swizzle blocks, after scatter

typedef __attribute__((ext_vector_type(8))) short short8;   // 8 bf16 (4 VGPRs)
typedef __attribute__((ext_vector_type(4))) float f32x4;    // MFMA C/D
union FragU { uint4 u; short8 s; };

__device__ __forceinline__ float leaky(float v){ return v > 0.f ? v : NEG * v; }

// fp32 -> bf16 round-to-nearest-even (no NaNs in this workload)
__device__ __forceinline__ unsigned int f2bf(float f){
  unsigned int u = __float_as_uint(f);
  u += 0x7fffu + ((u >> 16) & 1u);
  return u >> 16;
}
__device__ __forceinline__ unsigned int pack2bf(float a, float b){
  return f2bf(a) | (f2bf(b) << 16);
}
__device__ __forceinline__ float bflo(unsigned int u){ return __uint_as_float(u << 16); }
__device__ __forceinline__ float bfhi(unsigned int u){ return __uint_as_float(u & 0xffff0000u); }
__device__ __forceinline__ float bfus(unsigned short u){ return __uint_as_float((unsigned int)u << 16); }

// async 16B global->LDS (DMA, no VGPR round-trip). LDS dest = uniform base + lane*16.
__device__ __forceinline__ void gld_lds16(const void* g, void* l){
  __builtin_amdgcn_global_load_lds((const __attribute__((address_space(1))) unsigned int*)g,
                                   (__attribute__((address_space(3))) unsigned int*)l,
                                   16, 0, 0);
}

// K0: blocks 0..SCB-1 = XCD-partitioned ELL scatter, FOUR edges per lane per
// iteration (int4 dst read; src loads stay conditional so bytes don't grow).
// Blocks SCB.. = W1/W2 MFMA-fragment prep (tiny, backfills behind the scatter).
__global__ __launch_bounds__(256) void k_prep(const float* __restrict__ W1,
                                              uint4* __restrict__ W1bfs,
                                              const float* __restrict__ W2,
                                              uint4* __restrict__ W2bfs,
                                              const int* __restrict__ ei,
                                              int* __restrict__ cnt,
                                              int* __restrict__ srcp){
  const int tid = threadIdx.x;
  if (blockIdx.x < SCB){
    const int part = blockIdx.x & 7, rank = blockIdx.x >> 3;   // b&7 == XCD (round-robin)
    const int lo = part * NP_N, hi = lo + NP_N;
    const int4* dp = (const int4*)(ei + EE);                   // dst quads, 16B-aligned
    for (int e4 = rank * 256 + tid; e4 < EE / 4; e4 += 256 * 256){
      const int4 d4 = dp[e4];
      const int eb = 4 * e4;
      if (d4.x >= lo && d4.x < hi){
        int s = ei[eb];
        int pos = atomicAdd(&cnt[d4.x], 1);
        if (pos < CAP) srcp[d4.x * CAP + pos] = s;   // clamp guard (never hit per Poisson tail)
      }
      if (d4.y >= lo && d4.y < hi){
        int s = ei[eb + 1];
        int pos = atomicAdd(&cnt[d4.y], 1);
        if (pos < CAP) srcp[d4.y * CAP + pos] = s;
      }
      if (d4.z >= lo && d4.z < hi){
        int s = ei[eb + 2];
        int pos = atomicAdd(&cnt[d4.z], 1);
        if (pos < CAP) srcp[d4.z * CAP + pos] = s;
      }
      if (d4.w >= lo && d4.w < hi){
        int s = ei[eb + 3];
        int pos = atomicAdd(&cnt[d4.w], 1);
        if (pos < CAP) srcp[d4.w * CAP + pos] = s;
      }
    }
    return;
  }
  const int pb = blockIdx.x - SCB;
  if (pb < 16){   // W1 (fp32 [256][128]) -> MFMA B-fragments (bf16)
    int f = pb * 256 + tid;   // 0..4095
    int lane = f & 63, nt = (f >> 6) & 7, kt = f >> 9;
    int quad = lane >> 4, l16 = lane & 15;
    const float* src = W1 + (size_t)(kt * 32 + quad * 8) * HC + nt * 16 + l16;
    unsigned int p[4];
#pragma unroll
    for (int jj = 0; jj < 4; jj++)
      p[jj] = pack2bf(src[(size_t)(2 * jj) * HC], src[(size_t)(2 * jj + 1) * HC]);
    W1bfs[f] = make_uint4(p[0], p[1], p[2], p[3]);
    return;
  }
  // W2 (fp32 [128][40]) -> MFMA B-fragments, N padded to 48 (3 nt tiles)
  int f = (pb - 16) * 256 + tid;   // 0..767 = 12 fragments x 64 lanes
  int lane = f & 63, frag = f >> 6;        // frag = kt*3 + nt
  int kt = frag / 3, nt = frag - kt * 3;
  int quad = lane >> 4, l16 = lane & 15;
  int n = nt * 16 + l16;                   // output col, pad >= NC with zeros
  int k0 = kt * 32 + quad * 8;
  unsigned int p[4];
#pragma unroll
  for (int jj = 0; jj < 4; jj++){
    float v0 = (n < NC) ? W2[(size_t)(k0 + 2 * jj) * NC + n] : 0.f;
    float v1 = (n < NC) ? W2[(size_t)(k0 + 2 * jj + 1) * NC + n] : 0.f;
    p[jj] = pack2bf(v0, v1);
  }
  W2bfs[f] = make_uint4(p[0], p[1], p[2], p[3]);
}

// K1: async-LDS GEMM h1(bf16)[N,128] = x @ W1, bf16 MFMA 16x16x32, BARRIER-FREE.
// Each wave stages its OWN 16 x-rows via 16 global_load_lds (zero VGPR, all async),
// one vmcnt(0), then MFMA from LDS. Source granules pre-swizzled (g ^ (row&7)) so
// the linear DMA write yields 32-bank-spread ds_read_b128.
__global__ __launch_bounds__(256, 2) void k_gemm1(const float* __restrict__ x,
                                                  const uint4* __restrict__ W1bfs,
                                                  const float* __restrict__ att_s,
                                                  const float* __restrict__ att_d,
                                                  unsigned short* __restrict__ h1b,
                                                  float* __restrict__ as1,
                                                  float* __restrict__ ad1){
  __shared__ float xs[BM * FIN];   // 64 KB; wave w owns rows [w*16, w*16+16)
  const int tid = threadIdx.x;
  const int wave = tid >> 6, lane = tid & 63;
  const int quad = lane >> 4, l16 = lane & 15;
  const int m0 = blockIdx.x * BM;
  const int wr0 = wave * 16;

#pragma unroll
  for (int i = 0; i < 16; i++){
    int grow = m0 + wr0 + i; if (grow >= NN) grow = NN - 1;   // clamp (dup stage benign)
    const float* src = x + (size_t)grow * FIN + ((lane ^ (i & 7)) << 2);
    gld_lds16(src, &xs[(wr0 + i) * FIN]);
  }

  FragU bf[8];
#pragma unroll
  for (int nt = 0; nt < 8; nt++) bf[nt].u = W1bfs[nt * 64 + lane];

  asm volatile("s_waitcnt vmcnt(0)" ::: "memory");
  __builtin_amdgcn_sched_barrier(0);

  f32x4 acc[8];
#pragma unroll
  for (int t = 0; t < 8; t++) acc[t] = (f32x4){0.f, 0.f, 0.f, 0.f};

  const int swz = l16 & 7;
  const float* xrow = &xs[(wr0 + l16) * FIN];
#pragma unroll
  for (int kt = 0; kt < 8; kt++){
    FragU bn[8];
    if (kt < 7){
#pragma unroll
      for (int nt = 0; nt < 8; nt++)
        bn[nt].u = W1bfs[((kt + 1) * 8 + nt) * 64 + lane];
    }
    const int g0 = kt * 8 + quad * 2;
    const float4 a0 = *(const float4*)(xrow + ((g0 ^ swz) << 2));
    const float4 a1 = *(const float4*)(xrow + (((g0 + 1) ^ swz) << 2));
    FragU af;
    af.u = make_uint4(pack2bf(a0.x, a0.y), pack2bf(a0.z, a0.w),
                      pack2bf(a1.x, a1.y), pack2bf(a1.z, a1.w));
#pragma unroll
    for (int nt = 0; nt < 8; nt++)
      acc[nt] = __builtin_amdgcn_mfma_f32_16x16x32_bf16(af.s, bf[nt].s, acc[nt], 0, 0, 0);
    if (kt < 7){
#pragma unroll
      for (int nt = 0; nt < 8; nt++) bf[nt] = bn[nt];
    }
  }

  float sv[8], dv[8];
#pragma unroll
  for (int h = 0; h < 8; h++){ sv[h] = att_s[h * 16 + l16]; dv[h] = att_d[h * 16 + l16]; }
#pragma unroll
  for (int r = 0; r < 4; r++){
    const int gr = m0 + wr0 + quad * 4 + r;
    float s[8], d[8];
#pragma unroll
    for (int h = 0; h < 8; h++){ s[h] = acc[h][r] * sv[h]; d[h] = acc[h][r] * dv[h]; }
#pragma unroll
    for (int o = 1; o < 16; o <<= 1){
#pragma unroll
      for (int h = 0; h < 8; h++){ s[h] += __shfl_xor(s[h], o); d[h] += __shfl_xor(d[h], o); }
    }
    if (gr < NN){
#pragma unroll
      for (int h = 0; h < 8; h++)
        h1b[(size_t)gr * HC + h * 16 + l16] = (unsigned short)f2bf(acc[h][r]);
      if (l16 == 0){
        *(float4*)(as1 + gr * 8)     = make_float4(s[0], s[1], s[2], s[3]);
        *(float4*)(as1 + gr * 8 + 4) = make_float4(s[4], s[5], s[6], s[7]);
        *(float4*)(ad1 + gr * 8)     = make_float4(d[0], d[1], d[2], d[3]);
        *(float4*)(ad1 + gr * 8 + 4) = make_float4(d[4], d[5], d[6], d[7]);
      }
    }
  }
}

// K2: layer-1 aggregate, TWO NODES PER WAVE (unchanged — pinned at its
// memory-system floor; see journal). 4 waves/block = 8 nodes, NO barriers.
__global__ __launch_bounds__(256) void k_agg1(const int* __restrict__ srcp,
                                              const int* __restrict__ cnt,
                                              const float* __restrict__ as1,
                                              const float* __restrict__ ad1,
                                              const unsigned short* __restrict__ h1b,
                                              const float* __restrict__ b1,
                                              unsigned short* __restrict__ h2b){
  __shared__ float wls[4][2][64][8];   // 16 KB [wave][node][edge][head]
  __shared__ int   sls[4][2][64];      // prescaled s<<5 (uint2 row base)
  __shared__ float dls[4][2][8];       // denominators per node per head
  const int lane = threadIdx.x & 63, w = threadIdx.x >> 6;
  const int nb = blockIdx.x * 8 + w * 2;
  const int h = lane >> 3, e8 = lane & 7;

  int degs[2], nEs[2];
#pragma unroll
  for (int j = 0; j < 2; j++){
    int d = cnt[nb + j]; if (d > CAP - 1) d = CAP - 1;
    degs[j] = d; nEs[j] = d + 1;
  }
  const int nEm = max(nEs[0], nEs[1]);
  int nCh = (nEm + 7) >> 3; if (nCh < 2) nCh = 2;   // shared -> both nodes zero-fill

#pragma unroll
  for (int j = 0; j < 2; j++){
    const int n = nb + j;
    const int deg = degs[j], nE = nEs[j];
    int sA = n;                                     // lanes >= deg hold self id
    if (lane < deg) sA = srcp[n * CAP + lane];      // coalesced row read
    sls[w][j][lane] = sA << 5;

    const float adg = ad1[n * 8 + h];
    float mx = -3.0e38f;
    for (int c = 0; c < nCh; c++){
      const int i = c * 8 + e8;
      const int s8 = sls[w][j][i] >> 2;             // == s*8
      const float v = (i < nE) ? leaky(as1[(size_t)(unsigned)(s8 + h)] + adg) : -3.0e38f;
      wls[w][j][i][h] = v;
      mx = fmaxf(mx, v);
    }
    mx = fmaxf(mx, __shfl_xor(mx, 1));
    mx = fmaxf(mx, __shfl_xor(mx, 2));
    mx = fmaxf(mx, __shfl_xor(mx, 4));

    float den = 0.f;
    for (int c = 0; c < nCh; c++){
      const int i = c * 8 + e8;
      const float v = wls[w][j][i][h];
      const float wt = (i < nE) ? __expf(v - mx) : 0.f;
      wls[w][j][i][h] = wt;                         // zeros out to nCh*8 >= nEm
      den += wt;
    }
    den += __shfl_xor(den, 1);
    den += __shfl_xor(den, 2);
    den += __shfl_xor(den, 4);
    if (e8 == 0) dls[w][j][h] = den;
  }

  // Phase B: node j = lane>>5; l32 = lane&31 -> channels 4*l32..4*l32+3 (head l32>>2).
  const int j = lane >> 5, l32 = lane & 31, hb = l32 >> 2;
  const uint2* hp = (const uint2*)h1b;
  float a0 = 0.f, a1 = 0.f, a2 = 0.f, a3 = 0.f;
  {
    uint2 u[16]; float q[16];
#pragma unroll
    for (int i = 0; i < 16; i++){
      u[i] = hp[(size_t)(unsigned)(sls[w][j][i] + l32)];
      q[i] = wls[w][j][i][hb];                      // ==0 beyond nE (nCh>=2 covers 16)
    }
#pragma unroll
    for (int i = 0; i < 16; i++){
      a0 += q[i] * bflo(u[i].x); a1 += q[i] * bfhi(u[i].x);
      a2 += q[i] * bflo(u[i].y); a3 += q[i] * bfhi(u[i].y);
    }
  }
  for (int i0 = 16; i0 < nEm; i0 += 8){             // wave-uniform; i < nCh*8 always
    uint2 uu[8]; float qq[8];
#pragma unroll
    for (int t = 0; t < 8; t++){
      const int i = i0 + t;
      uu[t] = hp[(size_t)(unsigned)(sls[w][j][i] + l32)];
      qq[t] = wls[w][j][i][hb];
    }
#pragma unroll
    for (int t = 0; t < 8; t++){
      a0 += qq[t] * bflo(uu[t].x); a1 += qq[t] * bfhi(uu[t].x);
      a2 += qq[t] * bflo(uu[t].y); a3 += qq[t] * bfhi(uu[t].y);
    }
  }

  const int n = nb + j;
  const float invd = 1.f / (dls[w][j][hb] + 1e-16f);
  const float4 bb = *(const float4*)(b1 + 4 * l32);
  float o0 = a0 * invd + bb.x;
  float o1 = a1 * invd + bb.y;
  float o2 = a2 * invd + bb.z;
  float o3 = a3 * invd + bb.w;
  o0 = o0 > 0.f ? o0 : (__expf(o0) - 1.f);          // ELU
  o1 = o1 > 0.f ? o1 : (__expf(o1) - 1.f);
  o2 = o2 > 0.f ? o2 : (__expf(o2) - 1.f);
  o3 = o3 > 0.f ? o3 : (__expf(o3) - 1.f);
  uint2 pk; pk.x = pack2bf(o0, o1); pk.y = pack2bf(o2, o3);
  ((uint2*)h2b)[(size_t)n * 32 + l32] = pk;
}

// K3: MFMA GEMM g(bf16)[N,40] = h2(bf16) @ W2 (N padded to 48), async-LDS staging
// of h2 rows (source-swizzled), fused att2 dots. Barrier-free.
__global__ __launch_bounds__(256, 3) void k_gemm2(const unsigned short* __restrict__ h2b,
                                                  const uint4* __restrict__ W2bfs,
                                                  const float* __restrict__ att_s2,
                                                  const float* __restrict__ att_d2,
                                                  unsigned short* __restrict__ gb,
                                                  float* __restrict__ as2,
                                                  float* __restrict__ ad2){
  __shared__ unsigned short h2s[BM2 * HC];   // 16 KB
  const int tid = threadIdx.x;
  const int wave = tid >> 6, lane = tid & 63;
  const int quad = lane >> 4, l16 = lane & 15;
  const int m0 = blockIdx.x * BM2;
  const int wr0 = wave * 16;

#pragma unroll
  for (int i = 0; i < 4; i++){
    const int rl = i * 4 + (lane >> 4);   // local row 0..15
    int grow = m0 + wr0 + rl; if (grow >= NN) grow = NN - 1;
    const int g = lane & 15;
    const unsigned short* src = h2b + (size_t)grow * HC + ((g ^ (rl & 7)) << 3);
    gld_lds16(src, &h2s[(wr0 + i * 4) * HC]);
  }

  FragU b2f[12];
#pragma unroll
  for (int f = 0; f < 12; f++) b2f[f].u = W2bfs[f * 64 + lane];

  asm volatile("s_waitcnt vmcnt(0)" ::: "memory");
  __builtin_amdgcn_sched_barrier(0);

  f32x4 acc[3];
#pragma unroll
  for (int t = 0; t < 3; t++) acc[t] = (f32x4){0.f, 0.f, 0.f, 0.f};

  const int swz = l16 & 7;
  const unsigned short* hrow = &h2s[(wr0 + l16) * HC];
#pragma unroll
  for (int kt = 0; kt < 4; kt++){
    FragU af;
    af.u = *(const uint4*)(hrow + (((kt * 4 + quad) ^ swz) << 3));
#pragma unroll
    for (int nt = 0; nt < 3; nt++)
      acc[nt] = __builtin_amdgcn_mfma_f32_16x16x32_bf16(af.s, b2f[kt * 3 + nt].s, acc[nt], 0, 0, 0);
  }

  float sv[3], dv[3];
#pragma unroll
  for (int nt = 0; nt < 3; nt++){
    const int c = nt * 16 + l16;
    sv[nt] = (c < NC) ? att_s2[c] : 0.f;
    dv[nt] = (c < NC) ? att_d2[c] : 0.f;
  }
#pragma unroll
  for (int r = 0; r < 4; r++){
    const int gr = m0 + wr0 + quad * 4 + r;
    float s = acc[0][r] * sv[0] + acc[1][r] * sv[1] + acc[2][r] * sv[2];
    float d = acc[0][r] * dv[0] + acc[1][r] * dv[1] + acc[2][r] * dv[2];
#pragma unroll
    for (int o = 1; o < 16; o <<= 1){ s += __shfl_xor(s, o); d += __shfl_xor(d, o); }
    if (gr < NN){
#pragma unroll
      for (int nt = 0; nt < 3; nt++){
        const int c = nt * 16 + l16;
        if (c < NC) gb[(size_t)gr * NC + c] = (unsigned short)f2bf(acc[nt][r]);
      }
      if (l16 == 0){ as2[gr] = s; ad2[gr] = d; }
    }
  }
}

// K4: layer-2 aggregate, TWO NODES PER WAVE. Phase A (per node j): lane = edge,
// full-wave softmax. Phase B: half-wave per node; lane handles a CLASS PAIR via
// dword loads (each load instruction moves two 80B rows). float2 outputs.
// 4 waves/block = 8 nodes, NO barriers (intra-wave LDS only).
__global__ __launch_bounds__(256) void k_agg2(const int* __restrict__ srcp,
                                              const int* __restrict__ cnt,
                                              const float* __restrict__ as2,
                                              const float* __restrict__ ad2,
                                              const unsigned short* __restrict__ gb,
                                              const float* __restrict__ b2,
                                              float* __restrict__ out){
  __shared__ float wls[4][2][64];
  __shared__ int   sls[4][2][64];   // prescaled s*20 (dword index into gb)
  __shared__ float dls[4][2];
  const int lane = threadIdx.x & 63, w = threadIdx.x >> 6;
  const int nb = blockIdx.x * 8 + w * 2;

  int nEs[2];
#pragma unroll
  for (int j = 0; j < 2; j++){
    const int n = nb + j;
    int deg = cnt[n]; if (deg > CAP - 1) deg = CAP - 1;   // reserve slot for self
    nEs[j] = deg + 1;
    const bool act = (lane <= deg);
    int sA = n;                                   // lane==deg -> self; lanes>deg -> n
    if (lane < deg) sA = srcp[n * CAP + lane];
    sls[w][j][lane] = sA * 20;
    float v = act ? leaky(as2[sA] + ad2[n]) : -3.0e38f;
    float mx = v;
#pragma unroll
    for (int o = 1; o < 64; o <<= 1) mx = fmaxf(mx, __shfl_xor(mx, o));
    float wt = act ? __expf(v - mx) : 0.f;
    float den = wt;
#pragma unroll
    for (int o = 1; o < 64; o <<= 1) den += __shfl_xor(den, o);
    wls[w][j][lane] = wt;                         // 0 for lanes > deg
    if (lane == 0) dls[w][j] = den;
  }
  const int nEm = max(nEs[0], nEs[1]);

  // Phase B: node j = lane>>5; l32 = lane&31; classes {2cc, 2cc+1} (cc < 20 active).
  const int j = lane >> 5, l32 = lane & 31;
  const int cc = min(l32, 19);
  const unsigned int* gp = (const unsigned int*)gb;
  float a0 = 0.f, a1 = 0.f;
  {
    unsigned int u[16]; float q[16];
#pragma unroll
    for (int i = 0; i < 16; i++){
      u[i] = gp[(size_t)(unsigned)(sls[w][j][i] + cc)];
      q[i] = wls[w][j][i];                        // 0 beyond nE
    }
#pragma unroll
    for (int i = 0; i < 16; i++){ a0 += q[i] * bflo(u[i]); a1 += q[i] * bfhi(u[i]); }
  }
  for (int i0 = 16; i0 < nEm; i0 += 8){           // wave-uniform; i <= 63 always
    unsigned int uu[8]; float qq[8];
#pragma unroll
    for (int t = 0; t < 8; t++){
      const int i = i0 + t;
      uu[t] = gp[(size_t)(unsigned)(sls[w][j][i] + cc)];
      qq[t] = wls[w][j][i];
    }
#pragma unroll
    for (int t = 0; t < 8; t++){ a0 += qq[t] * bflo(uu[t]); a1 += qq[t] * bfhi(uu[t]); }
  }

  const int n = nb + j;
  const float invd = 1.f / (dls[w][j] + 1e-16f);
  const float2 bb = *(const float2*)(b2 + 2 * cc);
  const float f0 = a0 * invd + bb.x;
  const float f1 = a1 * invd + bb.y;
  const bool cl = (l32 < 20);
  if (cl) *(float2*)(out + (size_t)n * NC + 2 * cc) = make_float2(f0, f1);
  // log_softmax within the half-wave (20 active lanes x 2 classes each)
  float fm = cl ? fmaxf(f0, f1) : -3.4e38f;
#pragma unroll
  for (int o = 1; o < 32; o <<= 1) fm = fmaxf(fm, __shfl_xor(fm, o));
  float ex = cl ? (__expf(f0 - fm) + __expf(f1 - fm)) : 0.f;
#pragma unroll
  for (int o = 1; o < 32; o <<= 1) ex += __shfl_xor(ex, o);
  const float lse = fm + __logf(ex);
  if (cl) *(float2*)(out + (size_t)(NN * NC) + (size_t)n * NC + 2 * cc)
            = make_float2(f0 - lse, f1 - lse);
}

extern "C" void kernel_launch(void* const* d_in, const int* in_sizes, int n_in,
                              void* d_out, int out_size, void* d_ws, size_t ws_size,
                              hipStream_t stream){
  const float* x      = (const float*)d_in[0];
  const int*   ei     = (const int*)  d_in[1];
  const float* W1     = (const float*)d_in[3];
  const float* att_s1 = (const float*)d_in[4];
  const float* att_d1 = (const float*)d_in[5];
  const float* b1     = (const float*)d_in[6];
  const float* W2     = (const float*)d_in[7];
  const float* att_s2 = (const float*)d_in[8];
  const float* att_d2 = (const float*)d_in[9];
  const float* b2     = (const float*)d_in[10];
  float* out = (float*)d_out;

  char* wp = (char*)d_ws;
  uint4* W1bfs = (uint4*)wp;                 wp += (size_t)4096 * 16;      // 64 KB
  uint4* W2bfs = (uint4*)wp;                 wp += (size_t)768 * 16;       // 12 KB
  unsigned short* h1b = (unsigned short*)wp; wp += (size_t)NN * HC * 2;    // 12.8 MB
  unsigned short* h2b = (unsigned short*)wp; wp += (size_t)NN * HC * 2;    // 12.8 MB
  unsigned short* gb  = (unsigned short*)wp; wp += (size_t)NN * NC * 2;    // 4 MB
  float* as1 = (float*)wp;                   wp += (size_t)NN * HD * 4;
  float* ad1 = (float*)wp;                   wp += (size_t)NN * HD * 4;
  float* as2 = (float*)wp;                   wp += (size_t)NN * 4;
  float* ad2 = (float*)wp;                   wp += (size_t)NN * 4;
  int* cnt   = (int*)wp;                     wp += (size_t)NN * 4;
  int* srcp  = (int*)wp;                     wp += (size_t)NN * CAP * 4;   // 12.8 MB

  hipMemsetAsync(cnt, 0, (size_t)NN * sizeof(int), stream);
  k_prep  <<<SCB + PREPB, 256, 0, stream>>>(W1, W1bfs, W2, W2bfs, ei, cnt, srcp);
  k_gemm1 <<<GB1, 256, 0, stream>>>(x, W1bfs, att_s1, att_d1, h1b, as1, ad1);
  k_agg1  <<<NN / 8, 256, 0, stream>>>(srcp, cnt, as1, ad1, h1b, b1, h2b);
  k_gemm2 <<<(NN + BM2 - 1) / BM2, 256, 0, stream>>>(h2b, W2bfs, att_s2, att_d2, gb, as2, ad2);
  k_agg2  <<<NN / 8, 256, 0, stream>>>(srcp, cnt, as2, ad2, gb, b2, out);
}